// Round 18
// baseline (469.640 us; speedup 1.0000x reference)
//
#include <hip/hip_runtime.h>
#include <math.h>

#define Nn 15000
#define NP 15040   // padded node count (32-node gru tiles, no bounds checks)
#define Ee 30000
#define NB_E 118   // ceil(Ee/256)
#define EB8 469    // k_edge8 blocks (64 edges each)

// ---- workspace layout (float offsets) ----
// zero region (zeroed by k_setupAll each call):
#define OFF_AGG   0          // [NP*64]
#define OFF_DEG   962560     // [Nn]
#define ZERO_END  977560     // 244390 float4s
// written-before-read region:
#define OFF_OUT   977568     // [NP*64]
#define OFF_DINV  1940128    // [Nn]
#define OFF_AT    1955136    // [65*4096] i4-major: At[p][(i>>2)*256 + o*4 + (i&3)]
#define OFF_BT    2221376    // [65*4096]
#define OFF_PE    2496016    // [Ee] int
#define OFF_BH    2526016    // [NB_E*65] int
#define OFF_SS    2541376    // [Ee] int
#define OFF_SD    2571376    // [Ee] int
#define OFF_SA    2601376    // [Ee] float
#define OFF_SP    2631376    // [Ee] int
#define OFF_PK    2661376    // [7*4096] packed GRU weights
#define OFF_GMA   2690048    // [256]
#define OFF_GSA   2690304    // [256]
#define OFF_GRA   2690560    // [256*64]
#define OFF_GMB   2706944    // [256]
#define OFF_GSB   2707200    // [256]
#define OFF_GRB   2707456    // [256*64]
// transposed Set2Set / mem LSTM weights (coalesced reads):
#define OFF_TSA   2723968    // [64*256]
#define OFF_TSB   2740352    // [64*256]
#define OFF_TMA   2756736    // [64*256]
#define OFF_TMB   2773120    // [64*256]
// double-buffered s2s LSTM state:
#define OFF_HSA   2789504    // [64]
#define OFF_CSA   2789568    // [64]
#define OFF_HSB   2789632    // [64]
#define OFF_CSB   2789696    // [64]
#define WS_FLOATS 2789760

// k_setupAll block ranges
#define SA_L0_END   3760     // lin0 (3760*256 == NP*64)
#define SA_WT2_END  3872     // +112: pk  (7*4096)
#define SA_WT3_END  4128     // +256: tsa/tsb/tma/tmb (4*16384)
#define SA_Z_END    5083     // +955: zero region
#define SA_AB_END   6123     // +1040: AB build (65 patterns x 16 chunks)
#define SA_EP_END   6241     // +118: eprep
#define ZERO_F4     244390

__device__ __forceinline__ float sigf(float x) { return 1.0f / (1.0f + expf(-x)); }
__device__ __forceinline__ float bcast(float v, int l) {
    return __int_as_float(__builtin_amdgcn_readlane(__float_as_int(v), l));
}
__device__ __forceinline__ int bcasti(int v, int l) {
    return __builtin_amdgcn_readlane(v, l);
}

// fused setup: lin0 | pk | ts*/tm* | zero | AB(inline patterns) | eprep(inline patterns)
__global__ __launch_bounds__(256) void k_setupAll(
        const float* __restrict__ x, const float* __restrict__ l0w,
        const float* __restrict__ l0b, float* __restrict__ out,
        const float* __restrict__ e1w, const float* __restrict__ e1b,
        const float* __restrict__ e2w, const float* __restrict__ e2b,
        float* __restrict__ At, float* __restrict__ Bt,
        const float* __restrict__ rootw, const float* __restrict__ whh,
        const float* __restrict__ wih, float* __restrict__ pk,
        const float* __restrict__ swih, const float* __restrict__ swhh,
        const float* __restrict__ mwih,
        float* __restrict__ tsa, float* __restrict__ tsb,
        float* __restrict__ tma, float* __restrict__ tmb,
        float* __restrict__ zbase,
        const int* __restrict__ ei, const float* __restrict__ ea,
        float* __restrict__ deg, int* __restrict__ pe, int* __restrict__ bh) {
    int b = blockIdx.x, tid = threadIdx.x;
    if (b < SA_L0_END) {
        int idx = b*256 + tid;
        int n = idx >> 6, o = idx & 63;
        float vv = 0.f;
        if (n < Nn)
            vv = fmaxf(l0b[o] + x[n*3+0]*l0w[o*3+0] + x[n*3+1]*l0w[o*3+1]
                       + x[n*3+2]*l0w[o*3+2], 0.f);
        out[idx] = vv;
    } else if (b < SA_WT2_END) {
        int idx = (b - SA_L0_END)*256 + tid;   // < 7*4096
        int g = idx >> 12;
        int t2 = idx & 4095;
        int q4 = t2 >> 2, k = t2 & 3;
        int lane = q4 & 63;
        int i4 = q4 >> 6;
        int i = i4*4 + k;
        float vv;
        if (g == 0)      vv = rootw[i*64 + lane];
        else if (g < 4)  vv = whh[((g-1)*64 + lane)*64 + i];
        else             vv = wih[((g-4)*64 + lane)*64 + i];
        pk[idx] = vv;
    } else if (b < SA_WT3_END) {
        int idx = (b - SA_WT2_END)*256 + tid;   // < 4*16384
        int t2 = idx >> 14, r = idx & 16383;
        int i = r >> 8, g = r & 255;
        if (t2 == 0)      tsa[r] = swih[g*128 + i] + swhh[g*64 + i];
        else if (t2 == 1) tsb[r] = swih[g*128 + 64 + i];
        else if (t2 == 2) tma[r] = mwih[g*128 + i];
        else              tmb[r] = mwih[g*128 + 64 + i];
    } else if (b < SA_Z_END) {
        int idx = (b - SA_WT3_END)*256 + tid;
        if (idx < ZERO_F4)
            ((float4*)zbase)[idx] = make_float4(0.f, 0.f, 0.f, 0.f);
    } else if (b < SA_AB_END) {
        // ---- AB build with inline patterns; i4-major output layout ----
        __shared__ float t[64]; __shared__ int valid[64];
        __shared__ float sbp[65]; __shared__ int cnt;
        __shared__ float su[64], sv[64];
        int rel = b - SA_Z_END;
        int j = rel >> 4, qc = rel & 15;
        float w1 = 0.f, b1 = 0.f, tv = 0.f; int va = 0;
        if (tid < 64) {
            w1 = e1w[tid]; b1 = e1b[tid];
            if (w1 != 0.f) { tv = -b1 / w1; va = (tv > 0.f && tv < 1.f) ? 1 : 0; }
            t[tid] = tv; valid[tid] = va;
        }
        __syncthreads();
        if (tid < 64 && va) {
            int rank = 0;
            for (int kk = 0; kk < 64; ++kk)
                if (valid[kk] && (t[kk] < tv || (t[kk] == tv && kk < tid))) rank++;
            sbp[rank] = tv;
        }
        if (tid == 0) { int c = 0; for (int kk = 0; kk < 64; ++kk) c += valid[kk]; cnt = c; }
        __syncthreads();
        int m = cnt;
        if (j > m) return;
        if (tid < 64) {
            float lo = (j == 0) ? 0.f : sbp[j-1];
            float hi = (j == m) ? 1.f : sbp[j];
            float c = 0.5f * (lo + hi);
            int msk = (c * w1 + b1) > 0.f;
            su[tid] = msk ? w1 : 0.f;
            sv[tid] = msk ? b1 : 0.f;
        }
        __syncthreads();
        int q = qc*256 + tid;
        int i = q >> 6, o = q & 63;
        const float* row = e2w + q*64;
        float a = 0.f, bb = 0.f;
        #pragma unroll 8
        for (int k = 0; k < 64; ++k) { float w = row[k]; a = fmaf(su[k], w, a); bb = fmaf(sv[k], w, bb); }
        int oidx = j*4096 + (i >> 2)*256 + o*4 + (i & 3);
        At[oidx] = a;
        Bt[oidx] = bb + e2b[q];
    } else {
        // ---- eprep with inline patterns ----
        __shared__ float t[64]; __shared__ int valid[64];
        __shared__ float sbp[65]; __shared__ int cnt;
        __shared__ int lh[65];
        int eb = b - SA_AB_END;
        float w1 = 0.f, b1 = 0.f, tv = 0.f; int va = 0;
        if (tid < 64) {
            w1 = e1w[tid]; b1 = e1b[tid];
            if (w1 != 0.f) { tv = -b1 / w1; va = (tv > 0.f && tv < 1.f) ? 1 : 0; }
            t[tid] = tv; valid[tid] = va;
        }
        if (tid < 65) lh[tid] = 0;
        __syncthreads();
        if (tid < 64 && va) {
            int rank = 0;
            for (int kk = 0; kk < 64; ++kk)
                if (valid[kk] && (t[kk] < tv || (t[kk] == tv && kk < tid))) rank++;
            sbp[rank] = tv;
        }
        if (tid == 0) { int c = 0; for (int kk = 0; kk < 64; ++kk) c += valid[kk]; cnt = c; }
        __syncthreads();
        int m = cnt;
        int e = eb * 256 + tid;
        if (e < Ee) {
            atomicAdd(&deg[ei[Ee + e]], 1.0f);
            float a = ea[e];
            int p = 0;
            for (int jj = 0; jj < m; ++jj) p += (sbp[jj] <= a) ? 1 : 0;
            pe[e] = p;
            atomicAdd(&lh[p], 1);
        }
        __syncthreads();
        if (tid < 65) bh[eb*65 + tid] = lh[tid];
    }
}

// fused: dinv (blocks 0..58) | scatter with inline cursor scan (blocks 59..176)
__global__ __launch_bounds__(256) void k_scatter3(
        const float* __restrict__ deg, float* __restrict__ dinv,
        const int* __restrict__ ei, const float* __restrict__ ea,
        const int* __restrict__ pe, const int* __restrict__ bh,
        int* __restrict__ sS, int* __restrict__ sD,
        float* __restrict__ sA, int* __restrict__ sP) {
    int tid = threadIdx.x;
    if (blockIdx.x < 59) {
        int n = blockIdx.x * 256 + tid;
        if (n < Nn) dinv[n] = 1.0f / fmaxf(deg[n], 1.0f);
        return;
    }
    int eb = blockIdx.x - 59;
    __shared__ int stot[65], sown[65], sbase[65], cur[65];
    if (tid < 65) {
        int own = 0, tot = 0;
        for (int b2 = 0; b2 < NB_E; ++b2) {
            int v = bh[b2*65 + tid];
            if (b2 < eb) own += v;
            tot += v;
        }
        stot[tid] = tot; sown[tid] = own;
    }
    __syncthreads();
    if (tid == 0) {
        int run = 0;
        for (int j = 0; j < 65; ++j) { sbase[j] = run; run += stot[j]; }
    }
    __syncthreads();
    if (tid < 65) cur[tid] = sbase[tid] + sown[tid];
    __syncthreads();
    int e = eb * 256 + tid;
    if (e >= Ee) return;
    int p = pe[e];
    int pos = atomicAdd(&cur[p], 1);
    sS[pos] = ei[e]; sD[pos] = ei[Ee + e]; sA[pos] = ea[e]; sP[pos] = p;
}

// pattern-sorted edges; pattern A/B staged in LDS per contiguous segment.
// 64 edges/block, 8 waves x 8 edges, 32KB LDS -> 4 blocks/CU co-residency.
__global__ __launch_bounds__(512) void k_edge8(
        const int* __restrict__ sS, const int* __restrict__ sD,
        const float* __restrict__ sA, const int* __restrict__ sP,
        const float* __restrict__ out, const float* __restrict__ At,
        const float* __restrict__ Bt, const float* __restrict__ dinv,
        float* __restrict__ agg) {
    __shared__ __align__(16) float sW[8192];   // A[4096] then B[4096] = 32 KB
    __shared__ int spat[64];
    int tid = threadIdx.x, lane = tid & 63, w = tid >> 6;
    int e0b = blockIdx.x * 64;
    int nE = Ee - e0b; if (nE > 64) nE = 64;
    if (tid < 64) spat[tid] = (tid < nE) ? sP[e0b + tid] : -1;

    int je = w * 8;                       // wave's first edge offset in block
    int msrc = 0, mdst = 0; float ma = 0.f, mdv = 0.f;
    if (lane < 8 && je + lane < nE) {
        int eidx = e0b + je + lane;
        msrc = sS[eidx]; mdst = sD[eidx]; ma = sA[eidx]; mdv = dinv[mdst];
    }
    float hv[8], av[8], dv[8];
    #pragma unroll
    for (int j = 0; j < 8; ++j) hv[j] = out[bcasti(msrc, j)*64 + lane];
    #pragma unroll
    for (int j = 0; j < 8; ++j) { av[j] = bcast(ma, j); dv[j] = bcast(mdv, j); }
    __syncthreads();                      // spat visible

    int ss = 0;
    while (ss < nE) {
        int p = spat[ss];
        int se = ss + 1;
        while (se < nE && spat[se] == p) ++se;
        __syncthreads();                  // previous segment's sW readers done
        {
            const float4* srcA = (const float4*)(At + p*4096);
            const float4* srcB = (const float4*)(Bt + p*4096);
            float4* dA = (float4*)sW;
            float4* dB = (float4*)(sW + 4096);
            #pragma unroll
            for (int i = 0; i < 2; ++i) {
                dA[i*512 + tid] = srcA[i*512 + tid];
                dB[i*512 + tid] = srcB[i*512 + tid];
            }
        }
        __syncthreads();

        float acc[8];
        #pragma unroll
        for (int j = 0; j < 8; ++j) acc[j] = 0.f;
        const float4* A4p = (const float4*)sW;
        const float4* B4p = (const float4*)(sW + 4096);
        #pragma unroll 4
        for (int i4 = 0; i4 < 16; ++i4) {
            float4 a4 = A4p[i4*64 + lane];
            float4 b4 = B4p[i4*64 + lane];
            #pragma unroll
            for (int j = 0; j < 8; ++j) {
                float aj = av[j];
                float h;
                h = bcast(hv[j], i4*4+0); acc[j] = fmaf(h, fmaf(aj, a4.x, b4.x), acc[j]);
                h = bcast(hv[j], i4*4+1); acc[j] = fmaf(h, fmaf(aj, a4.y, b4.y), acc[j]);
                h = bcast(hv[j], i4*4+2); acc[j] = fmaf(h, fmaf(aj, a4.z, b4.z), acc[j]);
                h = bcast(hv[j], i4*4+3); acc[j] = fmaf(h, fmaf(aj, a4.w, b4.w), acc[j]);
            }
        }
        #pragma unroll
        for (int j = 0; j < 8; ++j) {
            int jj = je + j;
            if (jj >= ss && jj < se)
                atomicAdd(&agg[bcasti(mdst, j)*64 + lane], acc[j] * dv[j]);
        }
        ss = se;
    }
}

// fused NNConv-root + GRU: split-phase LDS staging (64KB -> 2 blocks/CU
// co-residency). 32-node tiles, 4 waves x 8 nodes, 470 blocks. unroll 4 is
// LOAD-BEARING (full unroll spills: r15).
__global__ __launch_bounds__(256, 2) void k_gru9b(
        float* __restrict__ out, float* __restrict__ agg,
        const float* __restrict__ pk, const float* __restrict__ convb,
        const float* __restrict__ gbih, const float* __restrict__ gbhh) {
    __shared__ __align__(16) float wL[4*4096];   // 64 KB
    int tid = threadIdx.x, lane = tid & 63, w = tid >> 6;
    int n0 = blockIdx.x*32 + w*8;

    float hv[8], av[8];
    #pragma unroll
    for (int k = 0; k < 8; ++k) hv[k] = out[(n0+k)*64 + lane];
    #pragma unroll
    for (int k = 0; k < 8; ++k) {
        int gi = (n0+k)*64 + lane;
        av[k] = agg[gi];
        agg[gi] = 0.f;
    }

    // ---- stage phase-A weights: root, whh r/z/n (64 KB) ----
    {
        const float4* src = (const float4*)pk;
        float4* dst = (float4*)wL;
        #pragma unroll
        for (int i = 0; i < 16; ++i) dst[i*256 + tid] = src[i*256 + tid];
    }
    __syncthreads();
    const float4* wL4 = (const float4*)wL;

    float mv[8], ghr[8], ghz[8], ghn[8];
    float a0[8], a1[8], a2[8], a3[8];
    #pragma unroll
    for (int k = 0; k < 8; ++k) { a0[k]=0.f; a1[k]=0.f; a2[k]=0.f; a3[k]=0.f; }
    #pragma unroll 4
    for (int i4 = 0; i4 < 16; ++i4) {
        float4 w0 = wL4[(0*16+i4)*64 + lane];
        float4 w1 = wL4[(1*16+i4)*64 + lane];
        float4 w2 = wL4[(2*16+i4)*64 + lane];
        float4 w3 = wL4[(3*16+i4)*64 + lane];
        #pragma unroll
        for (int k = 0; k < 8; ++k) {
            float h;
            h = bcast(hv[k], i4*4+0);
            a0[k]=fmaf(h,w0.x,a0[k]); a1[k]=fmaf(h,w1.x,a1[k]);
            a2[k]=fmaf(h,w2.x,a2[k]); a3[k]=fmaf(h,w3.x,a3[k]);
            h = bcast(hv[k], i4*4+1);
            a0[k]=fmaf(h,w0.y,a0[k]); a1[k]=fmaf(h,w1.y,a1[k]);
            a2[k]=fmaf(h,w2.y,a2[k]); a3[k]=fmaf(h,w3.y,a3[k]);
            h = bcast(hv[k], i4*4+2);
            a0[k]=fmaf(h,w0.z,a0[k]); a1[k]=fmaf(h,w1.z,a1[k]);
            a2[k]=fmaf(h,w2.z,a2[k]); a3[k]=fmaf(h,w3.z,a3[k]);
            h = bcast(hv[k], i4*4+3);
            a0[k]=fmaf(h,w0.w,a0[k]); a1[k]=fmaf(h,w1.w,a1[k]);
            a2[k]=fmaf(h,w2.w,a2[k]); a3[k]=fmaf(h,w3.w,a3[k]);
        }
    }
    float cbv = convb[lane];
    #pragma unroll
    for (int k = 0; k < 8; ++k) {
        mv[k] = fmaxf(a0[k] + av[k] + cbv, 0.f);
        ghr[k] = a1[k]; ghz[k] = a2[k]; ghn[k] = a3[k];
    }
    __syncthreads();   // all phase-A reads of wL done

    // ---- stage phase-B weights: wih r/z/n (48 KB, overwrite) ----
    {
        const float4* src = (const float4*)pk;
        float4* dst = (float4*)wL;
        #pragma unroll
        for (int i = 0; i < 12; ++i) dst[i*256 + tid] = src[4096 + i*256 + tid];
    }
    __syncthreads();

    #pragma unroll
    for (int k = 0; k < 8; ++k) { a0[k]=0.f; a1[k]=0.f; a2[k]=0.f; }
    #pragma unroll 4
    for (int i4 = 0; i4 < 16; ++i4) {
        float4 w4v = wL4[(0*16+i4)*64 + lane];
        float4 w5v = wL4[(1*16+i4)*64 + lane];
        float4 w6v = wL4[(2*16+i4)*64 + lane];
        #pragma unroll
        for (int k = 0; k < 8; ++k) {
            float h;
            h = bcast(mv[k], i4*4+0);
            a0[k]=fmaf(h,w4v.x,a0[k]); a1[k]=fmaf(h,w5v.x,a1[k]); a2[k]=fmaf(h,w6v.x,a2[k]);
            h = bcast(mv[k], i4*4+1);
            a0[k]=fmaf(h,w4v.y,a0[k]); a1[k]=fmaf(h,w5v.y,a1[k]); a2[k]=fmaf(h,w6v.y,a2[k]);
            h = bcast(mv[k], i4*4+2);
            a0[k]=fmaf(h,w4v.z,a0[k]); a1[k]=fmaf(h,w5v.z,a1[k]); a2[k]=fmaf(h,w6v.z,a2[k]);
            h = bcast(mv[k], i4*4+3);
            a0[k]=fmaf(h,w4v.w,a0[k]); a1[k]=fmaf(h,w5v.w,a1[k]); a2[k]=fmaf(h,w6v.w,a2[k]);
        }
    }

    float br  = gbih[lane]      + gbhh[lane];
    float bz  = gbih[64+lane]   + gbhh[64+lane];
    float bnI = gbih[128+lane];
    float bnH = gbhh[128+lane];
    #pragma unroll
    for (int k = 0; k < 8; ++k) {
        float r  = sigf(a0[k] + ghr[k] + br);
        float z  = sigf(a1[k] + ghz[k] + bz);
        float nn = tanhf(fmaf(r, ghn[k] + bnH, a2[k] + bnI));
        out[(n0+k)*64 + lane] = (1.f - z)*nn + z*hv[k];
    }
}

// Set2Set iteration: wave-reduce finalize + coalesced LSTM + partials.
// hs/cs double-buffered by parity.
__global__ __launch_bounds__(512) void k_s2s(
        const float* __restrict__ tsa, const float* __restrict__ tsb,
        const float* __restrict__ bih, const float* __restrict__ bhh,
        const float* __restrict__ hs_rd, const float* __restrict__ cs_rd,
        float* __restrict__ hs_wr, float* __restrict__ cs_wr,
        const float* __restrict__ out,
        const float* __restrict__ gmax_rd, const float* __restrict__ gsum_rd,
        const float* __restrict__ gr_rd,
        float* __restrict__ gmax_wr, float* __restrict__ gsum_wr,
        float* __restrict__ gr_wr, int it) {
    __shared__ float red[512], shs[64], scs[64], srv[64], sg[256];
    __shared__ float wred[8], zred[8];
    __shared__ float sm_m[8], sm_z[8], sm_r[8][64];
    int tid = threadIdx.x, lane = tid & 63, w = tid >> 6;
    if (it == 0) {
        if (tid < 64) { shs[tid] = 0.f; scs[tid] = 0.f; srv[tid] = 0.f; }
        __syncthreads();
    } else {
        float gm = (tid < 256) ? gmax_rd[tid] : -3.4e38f;
        float wm = gm;
        #pragma unroll
        for (int off = 32; off > 0; off >>= 1) wm = fmaxf(wm, __shfl_xor(wm, off, 64));
        if (lane == 0) wred[w] = wm;
        __syncthreads();
        float M = fmaxf(fmaxf(fmaxf(wred[0], wred[1]), fmaxf(wred[2], wred[3])),
                        fmaxf(fmaxf(wred[4], wred[5]), fmaxf(wred[6], wred[7])));
        float zt = (tid < 256) ? gsum_rd[tid] * expf(gm - M) : 0.f;
        #pragma unroll
        for (int off = 32; off > 0; off >>= 1) zt += __shfl_xor(zt, off, 64);
        if (lane == 0) zred[w] = zt;
        float racc = 0.f;
        for (int b2 = w; b2 < 256; b2 += 8)
            racc = fmaf(gr_rd[b2*64 + lane], expf(gmax_rd[b2] - M), racc);
        red[tid] = racc;
        if (tid < 64) { shs[tid] = hs_rd[tid]; scs[tid] = cs_rd[tid]; }
        __syncthreads();
        if (w == 0) {
            float Z = zred[0]+zred[1]+zred[2]+zred[3]+zred[4]+zred[5]+zred[6]+zred[7];
            float s = 0.f;
            #pragma unroll
            for (int k = 0; k < 8; ++k) s += red[k*64 + lane];
            srv[lane] = s / Z;
        }
        __syncthreads();
    }
    if (tid < 256) {
        float g = bih[tid] + bhh[tid];
        #pragma unroll 8
        for (int i = 0; i < 64; ++i)
            g += shs[i]*tsa[i*256 + tid] + srv[i]*tsb[i*256 + tid];
        sg[tid] = g;
    }
    __syncthreads();
    if (tid < 64) {
        float ii = sigf(sg[tid]), ff = sigf(sg[64+tid]);
        float gg = tanhf(sg[128+tid]), oo = sigf(sg[192+tid]);
        float c2 = ff*scs[tid] + ii*gg;
        float hn = oo*tanhf(c2);
        shs[tid] = hn;
        if (blockIdx.x == 0) { hs_wr[tid] = hn; cs_wr[tid] = c2; }
    }
    __syncthreads();
    float hsv = shs[lane];
    float m = -3.4e38f, Z2 = 0.f, racc2 = 0.f;
    for (int n = blockIdx.x*8 + w; n < Nn; n += 2048) {
        float ov = out[n*64 + lane];
        float p = ov * hsv;
        #pragma unroll
        for (int off = 32; off > 0; off >>= 1) p += __shfl_xor(p, off, 64);
        float mn = fmaxf(m, p);
        float sc = expf(m - mn);
        float t  = expf(p - mn);
        Z2 = fmaf(Z2, sc, t);
        racc2 = fmaf(racc2, sc, t*ov);
        m = mn;
    }
    if (lane == 0) { sm_m[w] = m; sm_z[w] = Z2; }
    sm_r[w][lane] = racc2;
    __syncthreads();
    if (w == 0) {
        float M = sm_m[0];
        #pragma unroll
        for (int j = 1; j < 8; ++j) M = fmaxf(M, sm_m[j]);
        float Zb = 0.f, rb = 0.f;
        #pragma unroll
        for (int j = 0; j < 8; ++j) {
            float e = expf(sm_m[j] - M);
            Zb = fmaf(sm_z[j], e, Zb);
            rb = fmaf(sm_r[j][lane], e, rb);
        }
        gr_wr[blockIdx.x*64 + lane] = rb;
        if (lane == 0) { gmax_wr[blockIdx.x] = M; gsum_wr[blockIdx.x] = Zb; }
    }
}

// final: wave-reduce finalize, mem-LSTM (h=c=0, transposed weights), lin1, lin3
__global__ __launch_bounds__(256) void k_final2(
        const float* __restrict__ tma, const float* __restrict__ tmb,
        const float* __restrict__ mbih, const float* __restrict__ mbhh,
        const float* __restrict__ hs,
        const float* __restrict__ gmax, const float* __restrict__ gsum,
        const float* __restrict__ gr,
        const float* __restrict__ l1w, const float* __restrict__ l1b,
        const float* __restrict__ l3w, const float* __restrict__ l3b,
        float* __restrict__ dout) {
    __shared__ float red[256], shs[64], srv[64], sg[256], shx[64], so[64];
    __shared__ float wred[4], zred[4];
    int tid = threadIdx.x, lane = tid & 63, w = tid >> 6;
    {
        float gm = gmax[tid];
        float wm = gm;
        #pragma unroll
        for (int off = 32; off > 0; off >>= 1) wm = fmaxf(wm, __shfl_xor(wm, off, 64));
        if (lane == 0) wred[w] = wm;
        __syncthreads();
        float M = fmaxf(fmaxf(wred[0], wred[1]), fmaxf(wred[2], wred[3]));
        float zt = gsum[tid] * expf(gm - M);
        #pragma unroll
        for (int off = 32; off > 0; off >>= 1) zt += __shfl_xor(zt, off, 64);
        if (lane == 0) zred[w] = zt;
        float racc = 0.f;
        for (int b2 = w; b2 < 256; b2 += 4)
            racc = fmaf(gr[b2*64 + lane], expf(gmax[b2] - M), racc);
        red[tid] = racc;
        if (tid < 64) shs[tid] = hs[tid];
        __syncthreads();
        if (w == 0) {
            float Z = zred[0]+zred[1]+zred[2]+zred[3];
            srv[lane] = (red[lane] + red[64+lane] + red[128+lane] + red[192+lane]) / Z;
        }
    }
    __syncthreads();
    {
        float g = mbih[tid] + mbhh[tid];
        #pragma unroll 8
        for (int i = 0; i < 64; ++i)
            g += shs[i]*tma[i*256 + tid] + srv[i]*tmb[i*256 + tid];
        sg[tid] = g;
    }
    __syncthreads();
    if (tid < 64) {
        float ii = sigf(sg[tid]);
        float gg = tanhf(sg[128+tid]);
        float oo = sigf(sg[192+tid]);
        float c2 = ii * gg;
        float hx = oo * tanhf(c2);
        shx[tid] = hx;
        dout[1 + tid] = hx;
        dout[65 + tid] = c2;
    }
    __syncthreads();
    if (tid < 64) {
        float a = l1b[tid];
        const float* wr = l1w + tid*64;
        #pragma unroll 8
        for (int i = 0; i < 64; ++i) a = fmaf(shx[i], wr[i], a);
        so[tid] = fmaxf(a, 0.f);
    }
    __syncthreads();
    if (tid == 0) {
        float v = l3b[0];
        for (int i = 0; i < 64; ++i) v = fmaf(so[i], l3w[i], v);
        dout[0] = v;
    }
}

extern "C" void kernel_launch(void* const* d_in, const int* in_sizes, int n_in,
                              void* d_out, int out_size, void* d_ws, size_t ws_size,
                              hipStream_t stream) {
    const float* x    = (const float*)d_in[0];
    const int*   ei   = (const int*)  d_in[1];
    const float* ea   = (const float*)d_in[2];
    const float* l0w  = (const float*)d_in[3];
    const float* l0b  = (const float*)d_in[4];
    const float* e1w  = (const float*)d_in[5];
    const float* e1b  = (const float*)d_in[6];
    const float* e2w  = (const float*)d_in[7];
    const float* e2b  = (const float*)d_in[8];
    const float* rootw= (const float*)d_in[9];
    const float* convb= (const float*)d_in[10];
    const float* gwih = (const float*)d_in[11];
    const float* gwhh = (const float*)d_in[12];
    const float* gbih = (const float*)d_in[13];
    const float* gbhh = (const float*)d_in[14];
    const float* swih = (const float*)d_in[15];
    const float* swhh = (const float*)d_in[16];
    const float* sbih = (const float*)d_in[17];
    const float* sbhh = (const float*)d_in[18];
    const float* mwih = (const float*)d_in[19];
    const float* mbih = (const float*)d_in[21];
    const float* mbhh = (const float*)d_in[22];
    const float* l1w  = (const float*)d_in[23];
    const float* l1b  = (const float*)d_in[24];
    const float* l3w  = (const float*)d_in[25];
    const float* l3b  = (const float*)d_in[26];

    float* ws   = (float*)d_ws;
    float* dout = (float*)d_out;
    if (ws_size < (size_t)WS_FLOATS * sizeof(float)) return;

    float* agg  = ws + OFF_AGG;
    float* deg  = ws + OFF_DEG;
    float* out  = ws + OFF_OUT;
    float* dinv = ws + OFF_DINV;
    float* At   = ws + OFF_AT;
    float* Bt   = ws + OFF_BT;
    int*   pe   = (int*)(ws + OFF_PE);
    int*   bh   = (int*)(ws + OFF_BH);
    int*   sS   = (int*)(ws + OFF_SS);
    int*   sD   = (int*)(ws + OFF_SD);
    float* sA   = ws + OFF_SA;
    int*   sP   = (int*)(ws + OFF_SP);
    float* pk   = ws + OFF_PK;
    float* gmA  = ws + OFF_GMA;
    float* gsA  = ws + OFF_GSA;
    float* grA  = ws + OFF_GRA;
    float* gmB  = ws + OFF_GMB;
    float* gsB  = ws + OFF_GSB;
    float* grB  = ws + OFF_GRB;
    float* tsa  = ws + OFF_TSA;
    float* tsb  = ws + OFF_TSB;
    float* tma  = ws + OFF_TMA;
    float* tmb  = ws + OFF_TMB;
    float* hsA  = ws + OFF_HSA;
    float* csA  = ws + OFF_CSA;
    float* hsB  = ws + OFF_HSB;
    float* csB  = ws + OFF_CSB;

    k_setupAll<<<SA_EP_END, 256, 0, stream>>>(x, l0w, l0b, out, e1w, e1b, e2w, e2b,
                                              At, Bt, rootw, gwhh, gwih, pk,
                                              swih, swhh, mwih, tsa, tsb, tma, tmb,
                                              ws + OFF_AGG, ei, ea, deg, pe, bh);
    k_scatter3<<<59 + NB_E, 256, 0, stream>>>(deg, dinv, ei, ea, pe, bh,
                                              sS, sD, sA, sP);

    for (int s = 0; s < 6; ++s) {
        k_edge8<<<EB8, 512, 0, stream>>>(sS, sD, sA, sP, out, At, Bt, dinv, agg);
        k_gru9b<<<NP/32, 256, 0, stream>>>(out, agg, pk, convb, gbih, gbhh);
    }

    for (int it = 0; it < 6; ++it) {
        float* gm_rd = (it & 1) ? gmA : gmB;   // unused at it=0
        float* gs_rd = (it & 1) ? gsA : gsB;
        float* gr_rd = (it & 1) ? grA : grB;
        float* hs_rd = (it & 1) ? hsA : hsB;
        float* cs_rd = (it & 1) ? csA : csB;
        float* gm_wr = (it & 1) ? gmB : gmA;
        float* gs_wr = (it & 1) ? gsB : gsA;
        float* gr_wr = (it & 1) ? grB : grA;
        float* hs_wr = (it & 1) ? hsB : hsA;
        float* cs_wr = (it & 1) ? csB : csA;
        k_s2s<<<256, 512, 0, stream>>>(tsa, tsb, sbih, sbhh, hs_rd, cs_rd,
                                       hs_wr, cs_wr, out,
                                       gm_rd, gs_rd, gr_rd, gm_wr, gs_wr, gr_wr, it);
    }

    // it=5 wrote the B partial buffers and hsB/csB
    k_final2<<<1, 256, 0, stream>>>(tma, tmb, mbih, mbhh, hsB, gmB, gsB, grB,
                                    l1w, l1b, l3w, l3b, dout);
}

// Round 19
// 419.749 us; speedup vs baseline: 1.1189x; 1.1189x over previous
//
#include <hip/hip_runtime.h>
#include <math.h>

#define Nn 15000
#define NP 15040   // padded node count (64-node gru tiles, no bounds checks)
#define Ee 30000
#define NB_E 118   // ceil(Ee/256)
#define EB7 938    // k_edge7 blocks (32 edges each)

// ---- workspace layout (float offsets) ----
// zero region (zeroed by k_setupAll each call):
#define OFF_AGG   0          // [NP*64]
#define OFF_DEG   962560     // [Nn]
#define ZERO_END  977560     // 244390 float4s
// written-before-read region:
#define OFF_OUT   977568     // [NP*64]
#define OFF_DINV  1940128    // [Nn]
#define OFF_AT    1955136    // [65*4096] i4-major: At[p][(i>>2)*256 + o*4 + (i&3)]
#define OFF_BT    2221376    // [65*4096]
#define OFF_PE    2496016    // [Ee] int
#define OFF_BH    2526016    // [NB_E*65] int
#define OFF_SS    2541376    // [Ee] int
#define OFF_SD    2571376    // [Ee] int
#define OFF_SA    2601376    // [Ee] float
#define OFF_SP    2631376    // [Ee] int
#define OFF_PK    2661376    // [7*4096] packed GRU weights
#define OFF_GMA   2690048    // [256]
#define OFF_GSA   2690304    // [256]
#define OFF_GRA   2690560    // [256*64]
#define OFF_GMB   2706944    // [256]
#define OFF_GSB   2707200    // [256]
#define OFF_GRB   2707456    // [256*64]
// transposed Set2Set / mem LSTM weights (coalesced reads):
#define OFF_TSA   2723968    // [64*256]
#define OFF_TSB   2740352    // [64*256]
#define OFF_TMA   2756736    // [64*256]
#define OFF_TMB   2773120    // [64*256]
// double-buffered s2s LSTM state:
#define OFF_HSA   2789504    // [64]
#define OFF_CSA   2789568    // [64]
#define OFF_HSB   2789632    // [64]
#define OFF_CSB   2789696    // [64]
#define WS_FLOATS 2789760

// k_setupAll block ranges
#define SA_L0_END   3760     // lin0 (3760*256 == NP*64)
#define SA_WT2_END  3872     // +112: pk  (7*4096)
#define SA_WT3_END  4128     // +256: tsa/tsb/tma/tmb (4*16384)
#define SA_Z_END    5083     // +955: zero region
#define SA_AB_END   6123     // +1040: AB build (65 patterns x 16 chunks)
#define SA_EP_END   6241     // +118: eprep
#define ZERO_F4     244390

__device__ __forceinline__ float sigf(float x) { return 1.0f / (1.0f + expf(-x)); }
__device__ __forceinline__ float bcast(float v, int l) {
    return __int_as_float(__builtin_amdgcn_readlane(__float_as_int(v), l));
}
__device__ __forceinline__ int bcasti(int v, int l) {
    return __builtin_amdgcn_readlane(v, l);
}

// fused setup: lin0 | pk | ts*/tm* | zero | AB(inline patterns) | eprep(inline patterns)
__global__ __launch_bounds__(256) void k_setupAll(
        const float* __restrict__ x, const float* __restrict__ l0w,
        const float* __restrict__ l0b, float* __restrict__ out,
        const float* __restrict__ e1w, const float* __restrict__ e1b,
        const float* __restrict__ e2w, const float* __restrict__ e2b,
        float* __restrict__ At, float* __restrict__ Bt,
        const float* __restrict__ rootw, const float* __restrict__ whh,
        const float* __restrict__ wih, float* __restrict__ pk,
        const float* __restrict__ swih, const float* __restrict__ swhh,
        const float* __restrict__ mwih,
        float* __restrict__ tsa, float* __restrict__ tsb,
        float* __restrict__ tma, float* __restrict__ tmb,
        float* __restrict__ zbase,
        const int* __restrict__ ei, const float* __restrict__ ea,
        float* __restrict__ deg, int* __restrict__ pe, int* __restrict__ bh) {
    int b = blockIdx.x, tid = threadIdx.x;
    if (b < SA_L0_END) {
        int idx = b*256 + tid;
        int n = idx >> 6, o = idx & 63;
        float vv = 0.f;
        if (n < Nn)
            vv = fmaxf(l0b[o] + x[n*3+0]*l0w[o*3+0] + x[n*3+1]*l0w[o*3+1]
                       + x[n*3+2]*l0w[o*3+2], 0.f);
        out[idx] = vv;
    } else if (b < SA_WT2_END) {
        int idx = (b - SA_L0_END)*256 + tid;   // < 7*4096
        int g = idx >> 12;
        int t2 = idx & 4095;
        int q4 = t2 >> 2, k = t2 & 3;
        int lane = q4 & 63;
        int i4 = q4 >> 6;
        int i = i4*4 + k;
        float vv;
        if (g == 0)      vv = rootw[i*64 + lane];
        else if (g < 4)  vv = whh[((g-1)*64 + lane)*64 + i];
        else             vv = wih[((g-4)*64 + lane)*64 + i];
        pk[idx] = vv;
    } else if (b < SA_WT3_END) {
        int idx = (b - SA_WT2_END)*256 + tid;   // < 4*16384
        int t2 = idx >> 14, r = idx & 16383;
        int i = r >> 8, g = r & 255;
        if (t2 == 0)      tsa[r] = swih[g*128 + i] + swhh[g*64 + i];
        else if (t2 == 1) tsb[r] = swih[g*128 + 64 + i];
        else if (t2 == 2) tma[r] = mwih[g*128 + i];
        else              tmb[r] = mwih[g*128 + 64 + i];
    } else if (b < SA_Z_END) {
        int idx = (b - SA_WT3_END)*256 + tid;
        if (idx < ZERO_F4)
            ((float4*)zbase)[idx] = make_float4(0.f, 0.f, 0.f, 0.f);
    } else if (b < SA_AB_END) {
        // ---- AB build with inline patterns; i4-major output layout ----
        __shared__ float t[64]; __shared__ int valid[64];
        __shared__ float sbp[65]; __shared__ int cnt;
        __shared__ float su[64], sv[64];
        int rel = b - SA_Z_END;
        int j = rel >> 4, qc = rel & 15;
        float w1 = 0.f, b1 = 0.f, tv = 0.f; int va = 0;
        if (tid < 64) {
            w1 = e1w[tid]; b1 = e1b[tid];
            if (w1 != 0.f) { tv = -b1 / w1; va = (tv > 0.f && tv < 1.f) ? 1 : 0; }
            t[tid] = tv; valid[tid] = va;
        }
        __syncthreads();
        if (tid < 64 && va) {
            int rank = 0;
            for (int kk = 0; kk < 64; ++kk)
                if (valid[kk] && (t[kk] < tv || (t[kk] == tv && kk < tid))) rank++;
            sbp[rank] = tv;
        }
        if (tid == 0) { int c = 0; for (int kk = 0; kk < 64; ++kk) c += valid[kk]; cnt = c; }
        __syncthreads();
        int m = cnt;
        if (j > m) return;
        if (tid < 64) {
            float lo = (j == 0) ? 0.f : sbp[j-1];
            float hi = (j == m) ? 1.f : sbp[j];
            float c = 0.5f * (lo + hi);
            int msk = (c * w1 + b1) > 0.f;
            su[tid] = msk ? w1 : 0.f;
            sv[tid] = msk ? b1 : 0.f;
        }
        __syncthreads();
        int q = qc*256 + tid;
        int i = q >> 6, o = q & 63;
        const float* row = e2w + q*64;
        float a = 0.f, bb = 0.f;
        #pragma unroll 8
        for (int k = 0; k < 64; ++k) { float w = row[k]; a = fmaf(su[k], w, a); bb = fmaf(sv[k], w, bb); }
        int oidx = j*4096 + (i >> 2)*256 + o*4 + (i & 3);
        At[oidx] = a;
        Bt[oidx] = bb + e2b[q];
    } else {
        // ---- eprep with inline patterns ----
        __shared__ float t[64]; __shared__ int valid[64];
        __shared__ float sbp[65]; __shared__ int cnt;
        __shared__ int lh[65];
        int eb = b - SA_AB_END;
        float w1 = 0.f, b1 = 0.f, tv = 0.f; int va = 0;
        if (tid < 64) {
            w1 = e1w[tid]; b1 = e1b[tid];
            if (w1 != 0.f) { tv = -b1 / w1; va = (tv > 0.f && tv < 1.f) ? 1 : 0; }
            t[tid] = tv; valid[tid] = va;
        }
        if (tid < 65) lh[tid] = 0;
        __syncthreads();
        if (tid < 64 && va) {
            int rank = 0;
            for (int kk = 0; kk < 64; ++kk)
                if (valid[kk] && (t[kk] < tv || (t[kk] == tv && kk < tid))) rank++;
            sbp[rank] = tv;
        }
        if (tid == 0) { int c = 0; for (int kk = 0; kk < 64; ++kk) c += valid[kk]; cnt = c; }
        __syncthreads();
        int m = cnt;
        int e = eb * 256 + tid;
        if (e < Ee) {
            atomicAdd(&deg[ei[Ee + e]], 1.0f);
            float a = ea[e];
            int p = 0;
            for (int jj = 0; jj < m; ++jj) p += (sbp[jj] <= a) ? 1 : 0;
            pe[e] = p;
            atomicAdd(&lh[p], 1);
        }
        __syncthreads();
        if (tid < 65) bh[eb*65 + tid] = lh[tid];
    }
}

// fused: dinv (blocks 0..58) | scatter with inline cursor scan (blocks 59..176)
__global__ __launch_bounds__(256) void k_scatter3(
        const float* __restrict__ deg, float* __restrict__ dinv,
        const int* __restrict__ ei, const float* __restrict__ ea,
        const int* __restrict__ pe, const int* __restrict__ bh,
        int* __restrict__ sS, int* __restrict__ sD,
        float* __restrict__ sA, int* __restrict__ sP) {
    int tid = threadIdx.x;
    if (blockIdx.x < 59) {
        int n = blockIdx.x * 256 + tid;
        if (n < Nn) dinv[n] = 1.0f / fmaxf(deg[n], 1.0f);
        return;
    }
    int eb = blockIdx.x - 59;
    __shared__ int stot[65], sown[65], sbase[65], cur[65];
    if (tid < 65) {
        int own = 0, tot = 0;
        for (int b2 = 0; b2 < NB_E; ++b2) {
            int v = bh[b2*65 + tid];
            if (b2 < eb) own += v;
            tot += v;
        }
        stot[tid] = tot; sown[tid] = own;
    }
    __syncthreads();
    if (tid == 0) {
        int run = 0;
        for (int j = 0; j < 65; ++j) { sbase[j] = run; run += stot[j]; }
    }
    __syncthreads();
    if (tid < 65) cur[tid] = sbase[tid] + sown[tid];
    __syncthreads();
    int e = eb * 256 + tid;
    if (e >= Ee) return;
    int p = pe[e];
    int pos = atomicAdd(&cur[p], 1);
    sS[pos] = ei[e]; sD[pos] = ei[Ee + e]; sA[pos] = ea[e]; sP[pos] = p;
}

// pattern-sorted edges; pattern A/B staged in LDS per contiguous segment
// (weights-in-LDS like k_gru9 — VGPR arrays spill on this compiler, r16 proof:
// VGPR_Count=76 with 128 declared -> scratch). LDS reads amortized over the
// wave's 8 edges (2 ds_read_b128 per i4 feed 96 VALU ops). 32 edges/block.
__global__ __launch_bounds__(256) void k_edge7(
        const int* __restrict__ sS, const int* __restrict__ sD,
        const float* __restrict__ sA, const int* __restrict__ sP,
        const float* __restrict__ out, const float* __restrict__ At,
        const float* __restrict__ Bt, const float* __restrict__ dinv,
        float* __restrict__ agg) {
    __shared__ __align__(16) float sW[8192];   // A[4096] then B[4096] = 32 KB
    __shared__ int spat[32];
    int tid = threadIdx.x, lane = tid & 63, w = tid >> 6;
    int e0b = blockIdx.x * 32;
    int nE = Ee - e0b; if (nE > 32) nE = 32;
    if (tid < 32) spat[tid] = (tid < nE) ? sP[e0b + tid] : -1;

    int je = w * 8;                       // wave's first edge offset in block
    int msrc = 0, mdst = 0; float ma = 0.f, mdv = 0.f;
    if (lane < 8 && je + lane < nE) {
        int eidx = e0b + je + lane;
        msrc = sS[eidx]; mdst = sD[eidx]; ma = sA[eidx]; mdv = dinv[mdst];
    }
    float hv[8], av[8], dv[8];
    #pragma unroll
    for (int j = 0; j < 8; ++j) hv[j] = out[bcasti(msrc, j)*64 + lane];
    #pragma unroll
    for (int j = 0; j < 8; ++j) { av[j] = bcast(ma, j); dv[j] = bcast(mdv, j); }
    __syncthreads();                      // spat visible

    int ss = 0;
    while (ss < nE) {
        int p = spat[ss];
        int se = ss + 1;
        while (se < nE && spat[se] == p) ++se;
        __syncthreads();                  // previous segment's sW readers done
        {
            const float4* srcA = (const float4*)(At + p*4096);
            const float4* srcB = (const float4*)(Bt + p*4096);
            float4* dA = (float4*)sW;
            float4* dB = (float4*)(sW + 4096);
            #pragma unroll
            for (int i = 0; i < 4; ++i) {
                dA[i*256 + tid] = srcA[i*256 + tid];
                dB[i*256 + tid] = srcB[i*256 + tid];
            }
        }
        __syncthreads();

        float acc[8];
        #pragma unroll
        for (int j = 0; j < 8; ++j) acc[j] = 0.f;
        const float4* A4p = (const float4*)sW;
        const float4* B4p = (const float4*)(sW + 4096);
        #pragma unroll 4
        for (int i4 = 0; i4 < 16; ++i4) {
            float4 a4 = A4p[i4*64 + lane];
            float4 b4 = B4p[i4*64 + lane];
            #pragma unroll
            for (int j = 0; j < 8; ++j) {
                float aj = av[j];
                float h;
                h = bcast(hv[j], i4*4+0); acc[j] = fmaf(h, fmaf(aj, a4.x, b4.x), acc[j]);
                h = bcast(hv[j], i4*4+1); acc[j] = fmaf(h, fmaf(aj, a4.y, b4.y), acc[j]);
                h = bcast(hv[j], i4*4+2); acc[j] = fmaf(h, fmaf(aj, a4.z, b4.z), acc[j]);
                h = bcast(hv[j], i4*4+3); acc[j] = fmaf(h, fmaf(aj, a4.w, b4.w), acc[j]);
            }
        }
        #pragma unroll
        for (int j = 0; j < 8; ++j) {
            int jj = je + j;
            if (jj >= ss && jj < se)
                atomicAdd(&agg[bcasti(mdst, j)*64 + lane], acc[j] * dv[j]);
        }
        ss = se;
    }
}

// fused NNConv-root + GRU: weights in LDS (112KB), wave owns 8 nodes end-to-end.
// unroll 4 on the weight loops is LOAD-BEARING: full unroll spills (r15: 395MB
// scratch traffic, 244us). VGPR 88, no spill at unroll 4.
__global__ __launch_bounds__(512, 2) void k_gru9(
        float* __restrict__ out, float* __restrict__ agg,
        const float* __restrict__ pk, const float* __restrict__ convb,
        const float* __restrict__ gbih, const float* __restrict__ gbhh) {
    __shared__ __align__(16) float wL[7*4096];   // 112 KB
    int tid = threadIdx.x, lane = tid & 63, w = tid >> 6;
    int n0 = blockIdx.x*64 + w*8;

    float hv[8], av[8];
    #pragma unroll
    for (int k = 0; k < 8; ++k) hv[k] = out[(n0+k)*64 + lane];
    #pragma unroll
    for (int k = 0; k < 8; ++k) {
        int gi = (n0+k)*64 + lane;
        av[k] = agg[gi];
        agg[gi] = 0.f;
    }

    {
        const float4* src = (const float4*)pk;
        float4* dst = (float4*)wL;
        #pragma unroll
        for (int i = 0; i < 14; ++i) dst[i*512 + tid] = src[i*512 + tid];
    }
    __syncthreads();
    const float4* wL4 = (const float4*)wL;

    float mv[8], ghr[8], ghz[8], ghn[8];
    float a0[8], a1[8], a2[8], a3[8];
    #pragma unroll
    for (int k = 0; k < 8; ++k) { a0[k]=0.f; a1[k]=0.f; a2[k]=0.f; a3[k]=0.f; }
    #pragma unroll 4
    for (int i4 = 0; i4 < 16; ++i4) {
        float4 w0 = wL4[(0*16+i4)*64 + lane];
        float4 w1 = wL4[(1*16+i4)*64 + lane];
        float4 w2 = wL4[(2*16+i4)*64 + lane];
        float4 w3 = wL4[(3*16+i4)*64 + lane];
        #pragma unroll
        for (int k = 0; k < 8; ++k) {
            float h;
            h = bcast(hv[k], i4*4+0);
            a0[k]=fmaf(h,w0.x,a0[k]); a1[k]=fmaf(h,w1.x,a1[k]);
            a2[k]=fmaf(h,w2.x,a2[k]); a3[k]=fmaf(h,w3.x,a3[k]);
            h = bcast(hv[k], i4*4+1);
            a0[k]=fmaf(h,w0.y,a0[k]); a1[k]=fmaf(h,w1.y,a1[k]);
            a2[k]=fmaf(h,w2.y,a2[k]); a3[k]=fmaf(h,w3.y,a3[k]);
            h = bcast(hv[k], i4*4+2);
            a0[k]=fmaf(h,w0.z,a0[k]); a1[k]=fmaf(h,w1.z,a1[k]);
            a2[k]=fmaf(h,w2.z,a2[k]); a3[k]=fmaf(h,w3.z,a3[k]);
            h = bcast(hv[k], i4*4+3);
            a0[k]=fmaf(h,w0.w,a0[k]); a1[k]=fmaf(h,w1.w,a1[k]);
            a2[k]=fmaf(h,w2.w,a2[k]); a3[k]=fmaf(h,w3.w,a3[k]);
        }
    }
    float cbv = convb[lane];
    #pragma unroll
    for (int k = 0; k < 8; ++k) {
        mv[k] = fmaxf(a0[k] + av[k] + cbv, 0.f);
        ghr[k] = a1[k]; ghz[k] = a2[k]; ghn[k] = a3[k];
    }

    #pragma unroll
    for (int k = 0; k < 8; ++k) { a0[k]=0.f; a1[k]=0.f; a2[k]=0.f; }
    #pragma unroll 4
    for (int i4 = 0; i4 < 16; ++i4) {
        float4 w4v = wL4[(4*16+i4)*64 + lane];
        float4 w5v = wL4[(5*16+i4)*64 + lane];
        float4 w6v = wL4[(6*16+i4)*64 + lane];
        #pragma unroll
        for (int k = 0; k < 8; ++k) {
            float h;
            h = bcast(mv[k], i4*4+0);
            a0[k]=fmaf(h,w4v.x,a0[k]); a1[k]=fmaf(h,w5v.x,a1[k]); a2[k]=fmaf(h,w6v.x,a2[k]);
            h = bcast(mv[k], i4*4+1);
            a0[k]=fmaf(h,w4v.y,a0[k]); a1[k]=fmaf(h,w5v.y,a1[k]); a2[k]=fmaf(h,w6v.y,a2[k]);
            h = bcast(mv[k], i4*4+2);
            a0[k]=fmaf(h,w4v.z,a0[k]); a1[k]=fmaf(h,w5v.z,a1[k]); a2[k]=fmaf(h,w6v.z,a2[k]);
            h = bcast(mv[k], i4*4+3);
            a0[k]=fmaf(h,w4v.w,a0[k]); a1[k]=fmaf(h,w5v.w,a1[k]); a2[k]=fmaf(h,w6v.w,a2[k]);
        }
    }

    float br  = gbih[lane]      + gbhh[lane];
    float bz  = gbih[64+lane]   + gbhh[64+lane];
    float bnI = gbih[128+lane];
    float bnH = gbhh[128+lane];
    #pragma unroll
    for (int k = 0; k < 8; ++k) {
        float r  = sigf(a0[k] + ghr[k] + br);
        float z  = sigf(a1[k] + ghz[k] + bz);
        float nn = tanhf(fmaf(r, ghn[k] + bnH, a2[k] + bnI));
        out[(n0+k)*64 + lane] = (1.f - z)*nn + z*hv[k];
    }
}

// Set2Set iteration: wave-reduce finalize + coalesced LSTM + partials.
// hs/cs double-buffered by parity.
__global__ __launch_bounds__(512) void k_s2s(
        const float* __restrict__ tsa, const float* __restrict__ tsb,
        const float* __restrict__ bih, const float* __restrict__ bhh,
        const float* __restrict__ hs_rd, const float* __restrict__ cs_rd,
        float* __restrict__ hs_wr, float* __restrict__ cs_wr,
        const float* __restrict__ out,
        const float* __restrict__ gmax_rd, const float* __restrict__ gsum_rd,
        const float* __restrict__ gr_rd,
        float* __restrict__ gmax_wr, float* __restrict__ gsum_wr,
        float* __restrict__ gr_wr, int it) {
    __shared__ float red[512], shs[64], scs[64], srv[64], sg[256];
    __shared__ float wred[8], zred[8];
    __shared__ float sm_m[8], sm_z[8], sm_r[8][64];
    int tid = threadIdx.x, lane = tid & 63, w = tid >> 6;
    if (it == 0) {
        if (tid < 64) { shs[tid] = 0.f; scs[tid] = 0.f; srv[tid] = 0.f; }
        __syncthreads();
    } else {
        float gm = (tid < 256) ? gmax_rd[tid] : -3.4e38f;
        float wm = gm;
        #pragma unroll
        for (int off = 32; off > 0; off >>= 1) wm = fmaxf(wm, __shfl_xor(wm, off, 64));
        if (lane == 0) wred[w] = wm;
        __syncthreads();
        float M = fmaxf(fmaxf(fmaxf(wred[0], wred[1]), fmaxf(wred[2], wred[3])),
                        fmaxf(fmaxf(wred[4], wred[5]), fmaxf(wred[6], wred[7])));
        float zt = (tid < 256) ? gsum_rd[tid] * expf(gm - M) : 0.f;
        #pragma unroll
        for (int off = 32; off > 0; off >>= 1) zt += __shfl_xor(zt, off, 64);
        if (lane == 0) zred[w] = zt;
        float racc = 0.f;
        for (int b2 = w; b2 < 256; b2 += 8)
            racc = fmaf(gr_rd[b2*64 + lane], expf(gmax_rd[b2] - M), racc);
        red[tid] = racc;
        if (tid < 64) { shs[tid] = hs_rd[tid]; scs[tid] = cs_rd[tid]; }
        __syncthreads();
        if (w == 0) {
            float Z = zred[0]+zred[1]+zred[2]+zred[3]+zred[4]+zred[5]+zred[6]+zred[7];
            float s = 0.f;
            #pragma unroll
            for (int k = 0; k < 8; ++k) s += red[k*64 + lane];
            srv[lane] = s / Z;
        }
        __syncthreads();
    }
    if (tid < 256) {
        float g = bih[tid] + bhh[tid];
        #pragma unroll 8
        for (int i = 0; i < 64; ++i)
            g += shs[i]*tsa[i*256 + tid] + srv[i]*tsb[i*256 + tid];
        sg[tid] = g;
    }
    __syncthreads();
    if (tid < 64) {
        float ii = sigf(sg[tid]), ff = sigf(sg[64+tid]);
        float gg = tanhf(sg[128+tid]), oo = sigf(sg[192+tid]);
        float c2 = ff*scs[tid] + ii*gg;
        float hn = oo*tanhf(c2);
        shs[tid] = hn;
        if (blockIdx.x == 0) { hs_wr[tid] = hn; cs_wr[tid] = c2; }
    }
    __syncthreads();
    float hsv = shs[lane];
    float m = -3.4e38f, Z2 = 0.f, racc2 = 0.f;
    for (int n = blockIdx.x*8 + w; n < Nn; n += 2048) {
        float ov = out[n*64 + lane];
        float p = ov * hsv;
        #pragma unroll
        for (int off = 32; off > 0; off >>= 1) p += __shfl_xor(p, off, 64);
        float mn = fmaxf(m, p);
        float sc = expf(m - mn);
        float t  = expf(p - mn);
        Z2 = fmaf(Z2, sc, t);
        racc2 = fmaf(racc2, sc, t*ov);
        m = mn;
    }
    if (lane == 0) { sm_m[w] = m; sm_z[w] = Z2; }
    sm_r[w][lane] = racc2;
    __syncthreads();
    if (w == 0) {
        float M = sm_m[0];
        #pragma unroll
        for (int j = 1; j < 8; ++j) M = fmaxf(M, sm_m[j]);
        float Zb = 0.f, rb = 0.f;
        #pragma unroll
        for (int j = 0; j < 8; ++j) {
            float e = expf(sm_m[j] - M);
            Zb = fmaf(sm_z[j], e, Zb);
            rb = fmaf(sm_r[j][lane], e, rb);
        }
        gr_wr[blockIdx.x*64 + lane] = rb;
        if (lane == 0) { gmax_wr[blockIdx.x] = M; gsum_wr[blockIdx.x] = Zb; }
    }
}

// final: wave-reduce finalize, mem-LSTM (h=c=0, transposed weights), lin1, lin3
__global__ __launch_bounds__(256) void k_final2(
        const float* __restrict__ tma, const float* __restrict__ tmb,
        const float* __restrict__ mbih, const float* __restrict__ mbhh,
        const float* __restrict__ hs,
        const float* __restrict__ gmax, const float* __restrict__ gsum,
        const float* __restrict__ gr,
        const float* __restrict__ l1w, const float* __restrict__ l1b,
        const float* __restrict__ l3w, const float* __restrict__ l3b,
        float* __restrict__ dout) {
    __shared__ float red[256], shs[64], srv[64], sg[256], shx[64], so[64];
    __shared__ float wred[4], zred[4];
    int tid = threadIdx.x, lane = tid & 63, w = tid >> 6;
    {
        float gm = gmax[tid];
        float wm = gm;
        #pragma unroll
        for (int off = 32; off > 0; off >>= 1) wm = fmaxf(wm, __shfl_xor(wm, off, 64));
        if (lane == 0) wred[w] = wm;
        __syncthreads();
        float M = fmaxf(fmaxf(wred[0], wred[1]), fmaxf(wred[2], wred[3]));
        float zt = gsum[tid] * expf(gm - M);
        #pragma unroll
        for (int off = 32; off > 0; off >>= 1) zt += __shfl_xor(zt, off, 64);
        if (lane == 0) zred[w] = zt;
        float racc = 0.f;
        for (int b2 = w; b2 < 256; b2 += 4)
            racc = fmaf(gr[b2*64 + lane], expf(gmax[b2] - M), racc);
        red[tid] = racc;
        if (tid < 64) shs[tid] = hs[tid];
        __syncthreads();
        if (w == 0) {
            float Z = zred[0]+zred[1]+zred[2]+zred[3];
            srv[lane] = (red[lane] + red[64+lane] + red[128+lane] + red[192+lane]) / Z;
        }
    }
    __syncthreads();
    {
        float g = mbih[tid] + mbhh[tid];
        #pragma unroll 8
        for (int i = 0; i < 64; ++i)
            g += shs[i]*tma[i*256 + tid] + srv[i]*tmb[i*256 + tid];
        sg[tid] = g;
    }
    __syncthreads();
    if (tid < 64) {
        float ii = sigf(sg[tid]);
        float gg = tanhf(sg[128+tid]);
        float oo = sigf(sg[192+tid]);
        float c2 = ii * gg;
        float hx = oo * tanhf(c2);
        shx[tid] = hx;
        dout[1 + tid] = hx;
        dout[65 + tid] = c2;
    }
    __syncthreads();
    if (tid < 64) {
        float a = l1b[tid];
        const float* wr = l1w + tid*64;
        #pragma unroll 8
        for (int i = 0; i < 64; ++i) a = fmaf(shx[i], wr[i], a);
        so[tid] = fmaxf(a, 0.f);
    }
    __syncthreads();
    if (tid == 0) {
        float v = l3b[0];
        for (int i = 0; i < 64; ++i) v = fmaf(so[i], l3w[i], v);
        dout[0] = v;
    }
}

extern "C" void kernel_launch(void* const* d_in, const int* in_sizes, int n_in,
                              void* d_out, int out_size, void* d_ws, size_t ws_size,
                              hipStream_t stream) {
    const float* x    = (const float*)d_in[0];
    const int*   ei   = (const int*)  d_in[1];
    const float* ea   = (const float*)d_in[2];
    const float* l0w  = (const float*)d_in[3];
    const float* l0b  = (const float*)d_in[4];
    const float* e1w  = (const float*)d_in[5];
    const float* e1b  = (const float*)d_in[6];
    const float* e2w  = (const float*)d_in[7];
    const float* e2b  = (const float*)d_in[8];
    const float* rootw= (const float*)d_in[9];
    const float* convb= (const float*)d_in[10];
    const float* gwih = (const float*)d_in[11];
    const float* gwhh = (const float*)d_in[12];
    const float* gbih = (const float*)d_in[13];
    const float* gbhh = (const float*)d_in[14];
    const float* swih = (const float*)d_in[15];
    const float* swhh = (const float*)d_in[16];
    const float* sbih = (const float*)d_in[17];
    const float* sbhh = (const float*)d_in[18];
    const float* mwih = (const float*)d_in[19];
    const float* mbih = (const float*)d_in[21];
    const float* mbhh = (const float*)d_in[22];
    const float* l1w  = (const float*)d_in[23];
    const float* l1b  = (const float*)d_in[24];
    const float* l3w  = (const float*)d_in[25];
    const float* l3b  = (const float*)d_in[26];

    float* ws   = (float*)d_ws;
    float* dout = (float*)d_out;
    if (ws_size < (size_t)WS_FLOATS * sizeof(float)) return;

    float* agg  = ws + OFF_AGG;
    float* deg  = ws + OFF_DEG;
    float* out  = ws + OFF_OUT;
    float* dinv = ws + OFF_DINV;
    float* At   = ws + OFF_AT;
    float* Bt   = ws + OFF_BT;
    int*   pe   = (int*)(ws + OFF_PE);
    int*   bh   = (int*)(ws + OFF_BH);
    int*   sS   = (int*)(ws + OFF_SS);
    int*   sD   = (int*)(ws + OFF_SD);
    float* sA   = ws + OFF_SA;
    int*   sP   = (int*)(ws + OFF_SP);
    float* pk   = ws + OFF_PK;
    float* gmA  = ws + OFF_GMA;
    float* gsA  = ws + OFF_GSA;
    float* grA  = ws + OFF_GRA;
    float* gmB  = ws + OFF_GMB;
    float* gsB  = ws + OFF_GSB;
    float* grB  = ws + OFF_GRB;
    float* tsa  = ws + OFF_TSA;
    float* tsb  = ws + OFF_TSB;
    float* tma  = ws + OFF_TMA;
    float* tmb  = ws + OFF_TMB;
    float* hsA  = ws + OFF_HSA;
    float* csA  = ws + OFF_CSA;
    float* hsB  = ws + OFF_HSB;
    float* csB  = ws + OFF_CSB;

    k_setupAll<<<SA_EP_END, 256, 0, stream>>>(x, l0w, l0b, out, e1w, e1b, e2w, e2b,
                                              At, Bt, rootw, gwhh, gwih, pk,
                                              swih, swhh, mwih, tsa, tsb, tma, tmb,
                                              ws + OFF_AGG, ei, ea, deg, pe, bh);
    k_scatter3<<<59 + NB_E, 256, 0, stream>>>(deg, dinv, ei, ea, pe, bh,
                                              sS, sD, sA, sP);

    for (int s = 0; s < 6; ++s) {
        k_edge7<<<EB7, 256, 0, stream>>>(sS, sD, sA, sP, out, At, Bt, dinv, agg);
        k_gru9 <<<NP/64, 512, 0, stream>>>(out, agg, pk, convb, gbih, gbhh);
    }

    for (int it = 0; it < 6; ++it) {
        float* gm_rd = (it & 1) ? gmA : gmB;   // unused at it=0
        float* gs_rd = (it & 1) ? gsA : gsB;
        float* gr_rd = (it & 1) ? grA : grB;
        float* hs_rd = (it & 1) ? hsA : hsB;
        float* cs_rd = (it & 1) ? csA : csB;
        float* gm_wr = (it & 1) ? gmB : gmA;
        float* gs_wr = (it & 1) ? gsB : gsA;
        float* gr_wr = (it & 1) ? grB : grA;
        float* hs_wr = (it & 1) ? hsB : hsA;
        float* cs_wr = (it & 1) ? csB : csA;
        k_s2s<<<256, 512, 0, stream>>>(tsa, tsb, sbih, sbhh, hs_rd, cs_rd,
                                       hs_wr, cs_wr, out,
                                       gm_rd, gs_rd, gr_rd, gm_wr, gs_wr, gr_wr, it);
    }

    // it=5 wrote the B partial buffers and hsB/csB
    k_final2<<<1, 256, 0, stream>>>(tma, tmb, mbih, mbhh, hsB, gmB, gsB, grB,
                                    l1w, l1b, l3w, l3b, dout);
}